// Round 3
// baseline (7429.528 us; speedup 1.0000x reference)
//
#include <hip/hip_runtime.h>
#include <cstddef>

// DFMNET: 2-layer LSTM (B=2048, T=256, I=64, H=128) + 6-layer KDN MLP.
// Round 3: runtime dtype-adaptive. A probe kernel detects, per float array,
// whether it is bf16 or fp32 (fp32 read as bf16 shorts shows huge/NaN values;
// genuine bf16 weights/x are bounded ~1). Flags in d_ws; all loads branch
// (wave-uniform). Output dtype follows x's dtype. Choreography identical to
// round 2 (audited): grid=128x512, 16 rows/WG, 8 waves x 16 h-cols, fp32 cell
// state, ping-pong LDS activations, streamed (L2-resident) weights.

typedef __attribute__((ext_vector_type(8))) short short8;
typedef __attribute__((ext_vector_type(4))) float float4v;

#define OFF_Y  ((size_t)0)
#define OFF_H2 ((size_t)2048*64)
#define OFF_R  ((size_t)2048*192)

__device__ __forceinline__ float bf2f(unsigned short u){
  union { unsigned int i; float f; } c; c.i = ((unsigned int)u) << 16; return c.f;
}
__device__ __forceinline__ unsigned short f2bf(float f){
  union { float f; unsigned int i; } c; c.f = f;
  unsigned int x = c.i;
  unsigned int r = (x + 0x7FFFu + ((x >> 16) & 1u)) >> 16;   // RNE
  return (unsigned short)r;
}
__device__ __forceinline__ float sig_(float x){ return 1.0f/(1.0f + __expf(-x)); }
__device__ __forceinline__ float tanh_(float x){ return 2.0f/(1.0f + __expf(-2.0f*x)) - 1.0f; }

#define MFMA16(a,b,c) __builtin_amdgcn_mfma_f32_16x16x32_bf16((a),(b),(c),0,0,0)

// load 8 contiguous elements (element offset `off`) as bf16 fragment
__device__ __forceinline__ short8 ldw(const void* W, size_t off, int f32){
  if (f32){
    const float* p = (const float*)W + off;
    union { short8 v; unsigned short u[8]; } r;
    #pragma unroll
    for (int j = 0; j < 8; j++) r.u[j] = f2bf(p[j]);
    return r.v;
  }
  return *(const short8*)((const unsigned short*)W + off);
}
// load 2 contiguous elements packed as 2 bf16 in a uint
__device__ __forceinline__ unsigned int ldx2(const void* x, size_t off, int f32){
  if (f32){
    const float* p = (const float*)x + off;
    return (unsigned int)f2bf(p[0]) | ((unsigned int)f2bf(p[1]) << 16);
  }
  return *(const unsigned int*)((const unsigned short*)x + off);
}
__device__ __forceinline__ float ld1(const void* x, size_t off, int f32){
  if (f32) return ((const float*)x)[off];
  return bf2f(((const unsigned short*)x)[off]);
}
__device__ __forceinline__ void st1(void* o, size_t off, float v, int f32){
  if (f32) ((float*)o)[off] = v;
  else     ((unsigned short*)o)[off] = f2bf(v);
}

// ---------------------------------------------------------------------------
// dtype probe: flags[a]=1 iff array a is fp32 (bf16-reinterpreted shorts huge)
// ---------------------------------------------------------------------------
__global__ void probe_kernel(const void* x,
                             const void* w1i, const void* w1h,
                             const void* w2i, const void* w2h,
                             const void* k0, const void* k1, const void* k2,
                             const void* k3, const void* k4, const void* k5,
                             int* flags)
{
  const void* arrs[11] = {x, w1i, w1h, w2i, w2h, k0, k1, k2, k3, k4, k5};
  const int lane = threadIdx.x & 63;
  for (int a = 0; a < 11; a++){
    const unsigned short* p = (const unsigned short*)arrs[a];
    int bad = 0;
    #pragma unroll
    for (int j = 0; j < 8; j++){
      float v = bf2f(p[lane*8 + j]);
      if (!(v > -1e3f && v < 1e3f)) bad = 1;   // also catches NaN/Inf patterns
    }
    unsigned long long m = __ballot(bad);
    if (lane == 0) flags[a] = (m != 0ull) ? 1 : 0;
  }
}

// ---------------------------------------------------------------------------
// LSTM persistent kernel (weights streamed, L2-resident)
// ---------------------------------------------------------------------------
__global__ __launch_bounds__(512, 2)
void lstm_kernel(const void* __restrict__ x,
                 const void* __restrict__ Wih1, const void* __restrict__ Whh1,
                 const unsigned short* __restrict__ bih1, const unsigned short* __restrict__ bhh1,
                 const void* __restrict__ Wih2, const void* __restrict__ Whh2,
                 const unsigned short* __restrict__ bih2, const unsigned short* __restrict__ bhh2,
                 const int* __restrict__ flags, void* __restrict__ out)
{
  __shared__ __align__(16) unsigned short A1s[2][16][200];  // [x(64)|h1(128)]
  __shared__ __align__(16) unsigned short A2s[2][16][264];  // [h1(128)|h2(128)]

  const int fx  = flags[0];
  const int f1i = flags[1], f1h = flags[2];
  const int f2i = flags[3], f2h = flags[4];
  const int fo  = fx;   // output dtype follows x

  const int tid  = threadIdx.x;
  const int w    = tid >> 6;
  const int lane = tid & 63;
  const int l15  = lane & 15;
  const int lq   = lane >> 4;
  const int r0   = blockIdx.x * 16;
  const int mycol = w*16 + l15;
  const int xm = tid >> 5;
  const int xc = (tid & 31) * 2;

  // biases: zeros in this dataset; bf16-read of fp32 zeros is also 0
  float b1[4], b2[4];
  #pragma unroll
  for (int q = 0; q < 4; q++){
    int n = q*128 + mycol;
    b1[q] = bf2f(bih1[n]) + bf2f(bhh1[n]);
    b2[q] = bf2f(bih2[n]) + bf2f(bhh2[n]);
  }

  for (int i = tid; i < 16*128; i += 512){
    int m = i >> 7, c = i & 127;
    A1s[0][m][64 + c]  = 0;
    A2s[0][m][128 + c] = 0;
  }
  *(unsigned int*)&A1s[0][xm][xc] =
      ldx2(x, (((size_t)(r0 + xm))*256 + 0)*64 + xc, fx);

  float c1r[4] = {0.f,0.f,0.f,0.f};
  float c2r[4] = {0.f,0.f,0.f,0.f};
  __syncthreads();

  for (int t = 0; t < 256; t++){
    const int buf = t & 1, nbuf = buf ^ 1;

    unsigned int xv = 0u;
    if (t < 255)
      xv = ldx2(x, (((size_t)(r0 + xm))*256 + (t+1))*64 + xc, fx);

    // ---- cell1: gates = [x_t | h1(t-1)] @ W1^T  (q = i,f,g,o)
    float4v acc[4];
    #pragma unroll
    for (int q = 0; q < 4; q++) acc[q] = (float4v){b1[q], b1[q], b1[q], b1[q]};
    #pragma unroll
    for (int kc = 0; kc < 6; kc++){
      short8 af = *(const short8*)&A1s[buf][l15][kc*32 + lq*8];
      #pragma unroll
      for (int q = 0; q < 4; q++){
        short8 wf;
        if (kc < 2) wf = ldw(Wih1, (size_t)(q*128 + mycol)*64  + kc*32     + lq*8, f1i);
        else        wf = ldw(Whh1, (size_t)(q*128 + mycol)*128 + (kc-2)*32 + lq*8, f1h);
        acc[q] = MFMA16(af, wf, acc[q]);
      }
    }

    unsigned short h1b[4];
    #pragma unroll
    for (int r = 0; r < 4; r++){
      float ig = sig_(acc[0][r]);
      float fg = sig_(acc[1][r]);
      float gg = tanh_(acc[2][r]);
      float og = sig_(acc[3][r]);
      c1r[r] = fg*c1r[r] + ig*gg;
      h1b[r] = f2bf(og * tanh_(c1r[r]));
    }
    #pragma unroll
    for (int r = 0; r < 4; r++){
      int row = lq*4 + r;
      A2s[buf][row][mycol]       = h1b[r];
      A1s[nbuf][row][64 + mycol] = h1b[r];
    }

    __syncthreads();   // h1(t) visible for cell2

    // ---- cell2: gates = [h1(t) | h2(t-1)] @ W2^T
    #pragma unroll
    for (int q = 0; q < 4; q++) acc[q] = (float4v){b2[q], b2[q], b2[q], b2[q]};
    #pragma unroll
    for (int kc = 0; kc < 8; kc++){
      short8 af = *(const short8*)&A2s[buf][l15][kc*32 + lq*8];
      #pragma unroll
      for (int q = 0; q < 4; q++){
        short8 wf;
        if (kc < 4) wf = ldw(Wih2, (size_t)(q*128 + mycol)*128 + kc*32     + lq*8, f2i);
        else        wf = ldw(Whh2, (size_t)(q*128 + mycol)*128 + (kc-4)*32 + lq*8, f2h);
        acc[q] = MFMA16(af, wf, acc[q]);
      }
    }

    unsigned short h2b[4];
    float h2f[4];
    #pragma unroll
    for (int r = 0; r < 4; r++){
      float ig = sig_(acc[0][r]);
      float fg = sig_(acc[1][r]);
      float gg = tanh_(acc[2][r]);
      float og = sig_(acc[3][r]);
      c2r[r] = fg*c2r[r] + ig*gg;
      h2f[r] = og * tanh_(c2r[r]);
      h2b[r] = f2bf(h2f[r]);
    }
    #pragma unroll
    for (int r = 0; r < 4; r++){
      int row = lq*4 + r;
      A2s[nbuf][row][128 + mycol] = h2b[r];
    }
    if (t < 255){
      *(unsigned int*)&A1s[nbuf][xm][xc] = xv;
    } else {
      #pragma unroll
      for (int r = 0; r < 4; r++){
        size_t grow = (size_t)(r0 + lq*4 + r);
        st1(out, OFF_H2 + grow*128 + mycol, h2f[r], fo);
        st1(out, OFF_R  + grow*192 + mycol, h2f[r], fo);
      }
    }
    __syncthreads();
  }

  // epilogue: r cols 128..191 = x[:, 255, :]
  {
    size_t off = (((size_t)(r0 + xm))*256 + 255)*64 + xc;
    float v0, v1;
    if (fx){ const float* p = (const float*)x + off; v0 = p[0]; v1 = p[1]; }
    else   { const unsigned short* p = (const unsigned short*)x + off;
             v0 = bf2f(p[0]); v1 = bf2f(p[1]); }
    st1(out, OFF_R + (size_t)(r0 + xm)*192 + 128 + xc,     v0, fo);
    st1(out, OFF_R + (size_t)(r0 + xm)*192 + 128 + xc + 1, v1, fo);
  }
}

// ---------------------------------------------------------------------------
// KDN MLP: r[2048,192] -> 128 x5 (ReLU) -> 64
// ---------------------------------------------------------------------------
__device__ __forceinline__ void kdn_layer(const float (*bin)[194], float (*bout)[194],
                                          const void* __restrict__ W,
                                          const unsigned short* __restrict__ bias,
                                          int K, int m, int grp, int f32)
{
  for (int j = 0; j < 8; j++){
    int n = grp*8 + j;
    float acc = bf2f(bias[n]);
    for (int k0 = 0; k0 < K; k0 += 8){
      short8 wv = ldw(W, (size_t)n*K + k0, f32);
      #pragma unroll
      for (int jj = 0; jj < 8; jj++)
        acc = fmaf(bf2f((unsigned short)wv[jj]), bin[m][k0 + jj], acc);
    }
    bout[m][n] = fmaxf(acc, 0.0f);
  }
}

__global__ __launch_bounds__(256)
void kdn_kernel(const void* __restrict__ Wk0, const unsigned short* __restrict__ bk0,
                const void* __restrict__ Wk1, const unsigned short* __restrict__ bk1,
                const void* __restrict__ Wk2, const unsigned short* __restrict__ bk2,
                const void* __restrict__ Wk3, const unsigned short* __restrict__ bk3,
                const void* __restrict__ Wk4, const unsigned short* __restrict__ bk4,
                const void* __restrict__ Wk5, const unsigned short* __restrict__ bk5,
                const int* __restrict__ flags, void* __restrict__ out)
{
  __shared__ float bufA[16][194];
  __shared__ float bufB[16][194];
  const int tid = threadIdx.x;
  const int r0  = blockIdx.x * 16;
  const int m   = tid & 15;
  const int grp = tid >> 4;

  const int fo = flags[0];
  const int fk[6] = {flags[5], flags[6], flags[7], flags[8], flags[9], flags[10]};

  for (int i = tid; i < 16*192; i += 256){
    int mm = i / 192, k = i % 192;
    bufA[mm][k] = ld1(out, OFF_R + (size_t)(r0 + mm)*192 + k, fo);
  }
  __syncthreads();

  kdn_layer(bufA, bufB, Wk0, bk0, 192, m, grp, fk[0]); __syncthreads();
  kdn_layer(bufB, bufA, Wk1, bk1, 128, m, grp, fk[1]); __syncthreads();
  kdn_layer(bufA, bufB, Wk2, bk2, 128, m, grp, fk[2]); __syncthreads();
  kdn_layer(bufB, bufA, Wk3, bk3, 128, m, grp, fk[3]); __syncthreads();
  kdn_layer(bufA, bufB, Wk4, bk4, 128, m, grp, fk[4]); __syncthreads();

  for (int j = 0; j < 4; j++){
    int n = grp*4 + j;
    float acc = bf2f(bk5[n]);
    for (int k0 = 0; k0 < 128; k0 += 8){
      short8 wv = ldw(Wk5, (size_t)n*128 + k0, fk[5]);
      #pragma unroll
      for (int jj = 0; jj < 8; jj++)
        acc = fmaf(bf2f((unsigned short)wv[jj]), bufB[m][k0 + jj], acc);
    }
    st1(out, OFF_Y + (size_t)(r0 + m)*64 + n, acc, fo);
  }
}

// ---------------------------------------------------------------------------
extern "C" void kernel_launch(void* const* d_in, const int* in_sizes, int n_in,
                              void* d_out, int out_size, void* d_ws, size_t ws_size,
                              hipStream_t stream)
{
  (void)in_sizes; (void)n_in; (void)ws_size; (void)out_size;

  const void* x    = d_in[0];
  const void* Wih1 = d_in[1];
  const void* Whh1 = d_in[2];
  const unsigned short* bih1 = (const unsigned short*)d_in[3];
  const unsigned short* bhh1 = (const unsigned short*)d_in[4];
  const void* Wih2 = d_in[5];
  const void* Whh2 = d_in[6];
  const unsigned short* bih2 = (const unsigned short*)d_in[7];
  const unsigned short* bhh2 = (const unsigned short*)d_in[8];
  const void* Wk0 = d_in[9];  const unsigned short* bk0 = (const unsigned short*)d_in[10];
  const void* Wk1 = d_in[11]; const unsigned short* bk1 = (const unsigned short*)d_in[12];
  const void* Wk2 = d_in[13]; const unsigned short* bk2 = (const unsigned short*)d_in[14];
  const void* Wk3 = d_in[15]; const unsigned short* bk3 = (const unsigned short*)d_in[16];
  const void* Wk4 = d_in[17]; const unsigned short* bk4 = (const unsigned short*)d_in[18];
  const void* Wk5 = d_in[19]; const unsigned short* bk5 = (const unsigned short*)d_in[20];

  int* flags = (int*)d_ws;

  hipLaunchKernelGGL(probe_kernel, dim3(1), dim3(64), 0, stream,
                     x, Wih1, Whh1, Wih2, Whh2,
                     Wk0, Wk1, Wk2, Wk3, Wk4, Wk5, flags);
  hipLaunchKernelGGL(lstm_kernel, dim3(128), dim3(512), 0, stream,
                     x, Wih1, Whh1, bih1, bhh1, Wih2, Whh2, bih2, bhh2,
                     flags, d_out);
  hipLaunchKernelGGL(kdn_kernel, dim3(128), dim3(256), 0, stream,
                     Wk0, bk0, Wk1, bk1, Wk2, bk2, Wk3, bk3, Wk4, bk4,
                     Wk5, bk5, flags, d_out);
}

// Round 4
// 1934.393 us; speedup vs baseline: 3.8408x; 3.8408x over previous
//
#include <hip/hip_runtime.h>
#include <cstddef>

// DFMNET: 2-layer LSTM (B=2048,T=256,I=64,H=128) + 6-layer KDN. Mixed/unknown
// input dtype handled by probe (round-3, verified). Round 4: one-time weight
// conversion to bf16 in d_ws; LSTM holds 48/56 weight frags in VGPRs, streams
// q3 (8 frags) per step straight-line from ws; KDN rewritten with MFMA.

typedef __attribute__((ext_vector_type(8))) short short8;
typedef __attribute__((ext_vector_type(4))) float float4v;

#define OFF_Y  ((size_t)0)
#define OFF_H2 ((size_t)2048*64)
#define OFF_R  ((size_t)2048*192)

// ---- d_ws byte offsets (all 64-aligned) ----
#define WS_FLAGS   0
#define WS_W1I     64           // [512][64]  bf16
#define WS_W1H     65600        // [512][128] bf16
#define WS_W2I     196672       // [512][128] bf16
#define WS_W2H     327744       // [512][128] bf16
#define WS_WK0     458816       // [128][192] bf16
#define WS_WK1     507968       // [128][128] bf16
#define WS_WK2     540736
#define WS_WK3     573504
#define WS_WK4     606272
#define WS_WK5     639040       // [64][128] bf16
#define WS_B1      655424       // [512] f32 (bih1+bhh1)
#define WS_B2      657472       // [512] f32
#define WS_BK0     659520       // [128] f32
#define WS_BK1     660032
#define WS_BK2     660544
#define WS_BK3     661056
#define WS_BK4     661568
#define WS_BK5     662080       // [64] f32
#define WS_RB      662336       // [2048][192] bf16

__device__ __forceinline__ float bf2f(unsigned short u){
  union { unsigned int i; float f; } c; c.i = ((unsigned int)u) << 16; return c.f;
}
__device__ __forceinline__ unsigned short f2bf(float f){
  union { float f; unsigned int i; } c; c.f = f;
  unsigned int x = c.i;
  unsigned int r = (x + 0x7FFFu + ((x >> 16) & 1u)) >> 16;   // RNE
  return (unsigned short)r;
}
__device__ __forceinline__ float sig_(float x){ return 1.0f/(1.0f + __expf(-x)); }
__device__ __forceinline__ float tanh_(float x){ return 2.0f/(1.0f + __expf(-2.0f*x)) - 1.0f; }

#define MFMA16(a,b,c) __builtin_amdgcn_mfma_f32_16x16x32_bf16((a),(b),(c),0,0,0)

__device__ __forceinline__ unsigned int ldx2(const void* x, size_t off, int f32){
  if (f32){
    const float* p = (const float*)x + off;
    return (unsigned int)f2bf(p[0]) | ((unsigned int)f2bf(p[1]) << 16);
  }
  return *(const unsigned int*)((const unsigned short*)x + off);
}
__device__ __forceinline__ float ld1f(const void* p, int i, int f32){
  if (f32) return ((const float*)p)[i];
  return bf2f(((const unsigned short*)p)[i]);
}
__device__ __forceinline__ void st1(void* o, size_t off, float v, int f32){
  if (f32) ((float*)o)[off] = v;
  else     ((unsigned short*)o)[off] = f2bf(v);
}

// ---------------------------------------------------------------------------
// dtype probe: flags[a]=1 iff array a is fp32 (verified round 3)
// ---------------------------------------------------------------------------
__global__ void probe_kernel(const void* x,
                             const void* w1i, const void* w1h,
                             const void* w2i, const void* w2h,
                             const void* k0, const void* k1, const void* k2,
                             const void* k3, const void* k4, const void* k5,
                             int* flags)
{
  const void* arrs[11] = {x, w1i, w1h, w2i, w2h, k0, k1, k2, k3, k4, k5};
  const int lane = threadIdx.x & 63;
  for (int a = 0; a < 11; a++){
    const unsigned short* p = (const unsigned short*)arrs[a];
    int bad = 0;
    #pragma unroll
    for (int j = 0; j < 8; j++){
      float v = bf2f(p[lane*8 + j]);
      if (!(v > -1e3f && v < 1e3f)) bad = 1;
    }
    unsigned long long m = __ballot(bad);
    if (lane == 0) flags[a] = (m != 0ull) ? 1 : 0;
  }
}

// ---------------------------------------------------------------------------
// convert: weights -> bf16 in ws; bias sums -> f32 in ws
// grid = 81 blocks x 256 thr; blocks 0..79 cover weights (4096 el each)
// ---------------------------------------------------------------------------
__device__ __forceinline__ void conv_range(const void* src, unsigned short* dst,
                                           int lo, int n, int f32, int t){
  int hi = lo + 4096; if (hi > n) hi = n;
  for (int i = lo + t; i < hi; i += 256)
    dst[i] = f32 ? f2bf(((const float*)src)[i]) : ((const unsigned short*)src)[i];
}

__global__ void convert_kernel(const void* w1i, const void* w1h,
                               const void* w2i, const void* w2h,
                               const void* k0, const void* k1, const void* k2,
                               const void* k3, const void* k4, const void* k5,
                               const void* bi1, const void* bh1,
                               const void* bi2, const void* bh2,
                               const void* bb0, const void* bb1, const void* bb2,
                               const void* bb3, const void* bb4, const void* bb5,
                               char* ws)
{
  const int* flags = (const int*)(ws + WS_FLAGS);
  const int b = blockIdx.x, t = threadIdx.x;
  if      (b <  8) conv_range(w1i, (unsigned short*)(ws+WS_W1I), (b-0)*4096, 32768, flags[1], t);
  else if (b < 24) conv_range(w1h, (unsigned short*)(ws+WS_W1H), (b-8)*4096, 65536, flags[2], t);
  else if (b < 40) conv_range(w2i, (unsigned short*)(ws+WS_W2I), (b-24)*4096, 65536, flags[3], t);
  else if (b < 56) conv_range(w2h, (unsigned short*)(ws+WS_W2H), (b-40)*4096, 65536, flags[4], t);
  else if (b < 62) conv_range(k0,  (unsigned short*)(ws+WS_WK0), (b-56)*4096, 24576, flags[5], t);
  else if (b < 66) conv_range(k1,  (unsigned short*)(ws+WS_WK1), (b-62)*4096, 16384, flags[6], t);
  else if (b < 70) conv_range(k2,  (unsigned short*)(ws+WS_WK2), (b-66)*4096, 16384, flags[7], t);
  else if (b < 74) conv_range(k3,  (unsigned short*)(ws+WS_WK3), (b-70)*4096, 16384, flags[8], t);
  else if (b < 78) conv_range(k4,  (unsigned short*)(ws+WS_WK4), (b-74)*4096, 16384, flags[9], t);
  else if (b < 80) conv_range(k5,  (unsigned short*)(ws+WS_WK5), (b-78)*4096,  8192, flags[10], t);
  else {
    // biases (zeros in dataset; dtype follows sibling weight flag)
    float* b1 = (float*)(ws+WS_B1);
    float* b2 = (float*)(ws+WS_B2);
    for (int i = t; i < 512; i += 256){
      b1[i] = ld1f(bi1, i, flags[1]) + ld1f(bh1, i, flags[2]);
      b2[i] = ld1f(bi2, i, flags[3]) + ld1f(bh2, i, flags[4]);
    }
    const void* bks[6] = {bb0, bb1, bb2, bb3, bb4, bb5};
    const size_t dof[6] = {WS_BK0, WS_BK1, WS_BK2, WS_BK3, WS_BK4, WS_BK5};
    for (int a = 0; a < 6; a++){
      int n = (a == 5) ? 64 : 128;
      float* d = (float*)(ws + dof[a]);
      for (int i = t; i < n; i += 256) d[i] = ld1f(bks[a], i, flags[5+a]);
    }
  }
}

// ---------------------------------------------------------------------------
// LSTM persistent kernel: 48 weight frags VGPR-resident, q3 streamed from ws
// ---------------------------------------------------------------------------
__global__ __launch_bounds__(512, 2)
void lstm_kernel(const void* __restrict__ x, const char* __restrict__ ws,
                 void* __restrict__ out)
{
  __shared__ __align__(16) unsigned short A1s[2][16][200];  // [x(64)|h1(128)]
  __shared__ __align__(16) unsigned short A2s[2][16][264];  // [h1(128)|h2(128)]

  const int* flags = (const int*)(ws + WS_FLAGS);
  const int fx = flags[0];
  const int fo = fx;   // output dtype follows x

  const int tid  = threadIdx.x;
  const int w    = tid >> 6;
  const int lane = tid & 63;
  const int l15  = lane & 15;
  const int lq   = lane >> 4;
  const int r0   = blockIdx.x * 16;
  const int mycol = w*16 + l15;
  const int xm = tid >> 5;
  const int xc = (tid & 31) * 2;

  const unsigned short* W1I = (const unsigned short*)(ws + WS_W1I);
  const unsigned short* W1H = (const unsigned short*)(ws + WS_W1H);
  const unsigned short* W2I = (const unsigned short*)(ws + WS_W2I);
  const unsigned short* W2H = (const unsigned short*)(ws + WS_W2H);
  unsigned short* RB = (unsigned short*)(ws + WS_RB);

  // ---- resident fragments (one-time, straight bf16 b128 loads)
  short8 w1[4][6];
  #pragma unroll
  for (int q = 0; q < 4; q++){
    const int n = q*128 + mycol;
    #pragma unroll
    for (int kc = 0; kc < 6; kc++){
      const unsigned short* p = (kc < 2) ? (W1I + (size_t)n*64  + kc*32     + lq*8)
                                         : (W1H + (size_t)n*128 + (kc-2)*32 + lq*8);
      w1[q][kc] = *(const short8*)p;
    }
  }
  short8 w2r[3][8];
  #pragma unroll
  for (int q = 0; q < 3; q++){
    const int n = q*128 + mycol;
    #pragma unroll
    for (int kc = 0; kc < 8; kc++){
      const unsigned short* p = (kc < 4) ? (W2I + (size_t)n*128 + kc*32     + lq*8)
                                         : (W2H + (size_t)n*128 + (kc-4)*32 + lq*8);
      w2r[q][kc] = *(const short8*)p;
    }
  }
  const unsigned short* sq3i = W2I + (size_t)(3*128 + mycol)*128 + lq*8;
  const unsigned short* sq3h = W2H + (size_t)(3*128 + mycol)*128 + lq*8;

  float b1[4], b2[4];
  #pragma unroll
  for (int q = 0; q < 4; q++){
    b1[q] = ((const float*)(ws + WS_B1))[q*128 + mycol];
    b2[q] = ((const float*)(ws + WS_B2))[q*128 + mycol];
  }

  for (int i = tid; i < 16*128; i += 512){
    int m = i >> 7, c = i & 127;
    A1s[0][m][64 + c]  = 0;
    A2s[0][m][128 + c] = 0;
  }
  *(unsigned int*)&A1s[0][xm][xc] =
      ldx2(x, (((size_t)(r0 + xm))*256 + 0)*64 + xc, fx);

  float c1r[4] = {0.f,0.f,0.f,0.f};
  float c2r[4] = {0.f,0.f,0.f,0.f};
  __syncthreads();

  for (int t = 0; t < 256; t++){
    const int buf = t & 1, nbuf = buf ^ 1;

    // early prefetch: x(t+1) and streamed q3 first half (consumed in cell2)
    unsigned int xv = 0u;
    if (t < 255)
      xv = ldx2(x, (((size_t)(r0 + xm))*256 + (t+1))*64 + xc, fx);
    short8 stq3[8];
    stq3[0] = *(const short8*)(sq3i + 0);
    stq3[1] = *(const short8*)(sq3i + 32);
    stq3[2] = *(const short8*)(sq3i + 64);
    stq3[3] = *(const short8*)(sq3i + 96);

    // ---- cell1: gates = [x_t | h1(t-1)] @ W1^T
    float4v acc[4];
    #pragma unroll
    for (int q = 0; q < 4; q++) acc[q] = (float4v){b1[q], b1[q], b1[q], b1[q]};
    #pragma unroll
    for (int kc = 0; kc < 6; kc++){
      short8 af = *(const short8*)&A1s[buf][l15][kc*32 + lq*8];
      #pragma unroll
      for (int q = 0; q < 4; q++)
        acc[q] = MFMA16(af, w1[q][kc], acc[q]);
    }

    // streamed q3 second half
    stq3[4] = *(const short8*)(sq3h + 0);
    stq3[5] = *(const short8*)(sq3h + 32);
    stq3[6] = *(const short8*)(sq3h + 64);
    stq3[7] = *(const short8*)(sq3h + 96);

    unsigned short h1b[4];
    #pragma unroll
    for (int r = 0; r < 4; r++){
      float ig = sig_(acc[0][r]);
      float fg = sig_(acc[1][r]);
      float gg = tanh_(acc[2][r]);
      float og = sig_(acc[3][r]);
      c1r[r] = fg*c1r[r] + ig*gg;
      h1b[r] = f2bf(og * tanh_(c1r[r]));
    }
    #pragma unroll
    for (int r = 0; r < 4; r++){
      int row = lq*4 + r;
      A2s[buf][row][mycol]       = h1b[r];
      A1s[nbuf][row][64 + mycol] = h1b[r];
    }

    __syncthreads();   // h1(t) visible for cell2

    // ---- cell2: gates = [h1(t) | h2(t-1)] @ W2^T  (q0-2 resident, q3 streamed)
    #pragma unroll
    for (int q = 0; q < 4; q++) acc[q] = (float4v){b2[q], b2[q], b2[q], b2[q]};
    #pragma unroll
    for (int kc = 0; kc < 8; kc++){
      short8 af = *(const short8*)&A2s[buf][l15][kc*32 + lq*8];
      acc[0] = MFMA16(af, w2r[0][kc], acc[0]);
      acc[1] = MFMA16(af, w2r[1][kc], acc[1]);
      acc[2] = MFMA16(af, w2r[2][kc], acc[2]);
      acc[3] = MFMA16(af, stq3[kc],   acc[3]);
    }

    unsigned short h2b[4];
    float h2f[4];
    #pragma unroll
    for (int r = 0; r < 4; r++){
      float ig = sig_(acc[0][r]);
      float fg = sig_(acc[1][r]);
      float gg = tanh_(acc[2][r]);
      float og = sig_(acc[3][r]);
      c2r[r] = fg*c2r[r] + ig*gg;
      h2f[r] = og * tanh_(c2r[r]);
      h2b[r] = f2bf(h2f[r]);
    }
    #pragma unroll
    for (int r = 0; r < 4; r++){
      int row = lq*4 + r;
      A2s[nbuf][row][128 + mycol] = h2b[r];
    }
    if (t < 255){
      *(unsigned int*)&A1s[nbuf][xm][xc] = xv;
    } else {
      #pragma unroll
      for (int r = 0; r < 4; r++){
        size_t grow = (size_t)(r0 + lq*4 + r);
        st1(out, OFF_H2 + grow*128 + mycol, h2f[r], fo);
        st1(out, OFF_R  + grow*192 + mycol, h2f[r], fo);
        RB[grow*192 + mycol] = h2b[r];
      }
    }
    __syncthreads();
  }

  // epilogue: r cols 128..191 = x[:, 255, :]
  {
    size_t off = (((size_t)(r0 + xm))*256 + 255)*64 + xc;
    float v0, v1;
    if (fx){ const float* p = (const float*)x + off; v0 = p[0]; v1 = p[1]; }
    else   { const unsigned short* p = (const unsigned short*)x + off;
             v0 = bf2f(p[0]); v1 = bf2f(p[1]); }
    size_t rrow = (size_t)(r0 + xm)*192 + 128 + xc;
    st1(out, OFF_R + rrow,     v0, fo);
    st1(out, OFF_R + rrow + 1, v1, fo);
    RB[rrow]     = f2bf(v0);
    RB[rrow + 1] = f2bf(v1);
  }
}

// ---------------------------------------------------------------------------
// KDN with MFMA: r[2048,192] -> 128 x5 (ReLU) -> 64. WG=256 thr (4 waves),
// M=16 rows, wave owns 32 cols (2 tiles) for N=128 layers, 16 cols for N=64.
// ---------------------------------------------------------------------------
__global__ __launch_bounds__(256)
void kdn_kernel(const char* __restrict__ ws, void* __restrict__ out)
{
  __shared__ __align__(16) unsigned short bufA[16][200];
  __shared__ __align__(16) unsigned short bufB[16][200];

  const int* flags = (const int*)(ws + WS_FLAGS);
  const int fo = flags[0];

  const int tid = threadIdx.x;
  const int w    = tid >> 6;
  const int lane = tid & 63;
  const int l15  = lane & 15;
  const int lq   = lane >> 4;
  const int r0  = blockIdx.x * 16;

  const unsigned short* RB = (const unsigned short*)(ws + WS_RB);

  // stage r rows (bf16)
  for (int i = tid; i < 1536; i += 256){
    int row = i / 96, c2 = (i % 96) * 2;
    *(unsigned int*)&bufA[row][c2] =
        *(const unsigned int*)&RB[(size_t)(r0 + row)*192 + c2];
  }
  __syncthreads();

  const unsigned short* WK[6] = {
    (const unsigned short*)(ws+WS_WK0), (const unsigned short*)(ws+WS_WK1),
    (const unsigned short*)(ws+WS_WK2), (const unsigned short*)(ws+WS_WK3),
    (const unsigned short*)(ws+WS_WK4), (const unsigned short*)(ws+WS_WK5)};
  const float* BK[6] = {
    (const float*)(ws+WS_BK0), (const float*)(ws+WS_BK1),
    (const float*)(ws+WS_BK2), (const float*)(ws+WS_BK3),
    (const float*)(ws+WS_BK4), (const float*)(ws+WS_BK5)};

  unsigned short (*src)[200] = bufA;
  unsigned short (*dst)[200] = bufB;

  #pragma unroll
  for (int l = 0; l < 5; l++){
    const int K = (l == 0) ? 192 : 128;
    const int nk = K / 32;
    #pragma unroll
    for (int tau = 0; tau < 2; tau++){
      const int n = w*32 + tau*16 + l15;
      float bv = BK[l][n];
      float4v acc = {bv, bv, bv, bv};
      for (int kc = 0; kc < nk; kc++){
        short8 af = *(const short8*)&src[l15][kc*32 + lq*8];
        short8 wf = *(const short8*)(WK[l] + (size_t)n*K + kc*32 + lq*8);
        acc = MFMA16(af, wf, acc);
      }
      #pragma unroll
      for (int r = 0; r < 4; r++)
        dst[lq*4 + r][n] = f2bf(fmaxf(acc[r], 0.0f));
    }
    __syncthreads();
    unsigned short (*tmp)[200] = src; src = dst; dst = tmp;
  }

  // final layer: N=64, no ReLU
  {
    const int n = w*16 + l15;
    float bv = BK[5][n];
    float4v acc = {bv, bv, bv, bv};
    #pragma unroll
    for (int kc = 0; kc < 4; kc++){
      short8 af = *(const short8*)&src[l15][kc*32 + lq*8];
      short8 wf = *(const short8*)(WK[5] + (size_t)n*128 + kc*32 + lq*8);
      acc = MFMA16(af, wf, acc);
    }
    #pragma unroll
    for (int r = 0; r < 4; r++)
      st1(out, OFF_Y + (size_t)(r0 + lq*4 + r)*64 + n, acc[r], fo);
  }
}

// ---------------------------------------------------------------------------
extern "C" void kernel_launch(void* const* d_in, const int* in_sizes, int n_in,
                              void* d_out, int out_size, void* d_ws, size_t ws_size,
                              hipStream_t stream)
{
  (void)in_sizes; (void)n_in; (void)ws_size; (void)out_size;

  const void* x    = d_in[0];
  const void* Wih1 = d_in[1];
  const void* Whh1 = d_in[2];
  const void* bih1 = d_in[3];
  const void* bhh1 = d_in[4];
  const void* Wih2 = d_in[5];
  const void* Whh2 = d_in[6];
  const void* bih2 = d_in[7];
  const void* bhh2 = d_in[8];
  const void* Wk0 = d_in[9];  const void* bk0 = d_in[10];
  const void* Wk1 = d_in[11]; const void* bk1 = d_in[12];
  const void* Wk2 = d_in[13]; const void* bk2 = d_in[14];
  const void* Wk3 = d_in[15]; const void* bk3 = d_in[16];
  const void* Wk4 = d_in[17]; const void* bk4 = d_in[18];
  const void* Wk5 = d_in[19]; const void* bk5 = d_in[20];

  char* ws = (char*)d_ws;

  hipLaunchKernelGGL(probe_kernel, dim3(1), dim3(64), 0, stream,
                     x, Wih1, Whh1, Wih2, Whh2,
                     Wk0, Wk1, Wk2, Wk3, Wk4, Wk5, (int*)(ws + WS_FLAGS));
  hipLaunchKernelGGL(convert_kernel, dim3(81), dim3(256), 0, stream,
                     Wih1, Whh1, Wih2, Whh2,
                     Wk0, Wk1, Wk2, Wk3, Wk4, Wk5,
                     bih1, bhh1, bih2, bhh2,
                     bk0, bk1, bk2, bk3, bk4, bk5, ws);
  hipLaunchKernelGGL(lstm_kernel, dim3(128), dim3(512), 0, stream,
                     x, ws, d_out);
  hipLaunchKernelGGL(kdn_kernel, dim3(128), dim3(256), 0, stream,
                     ws, d_out);
}

// Round 5
// 1640.910 us; speedup vs baseline: 4.5277x; 1.1789x over previous
//
#include <hip/hip_runtime.h>
#include <cstddef>

// DFMNET: 2-layer LSTM (B=2048,T=256,I=64,H=128) + 6-layer KDN. Probe-detected
// per-array dtype (round-3, verified). Round 5: make weight residency FIT:
// 176 regs resident (44 frags) + 4 frags/wave parked in LDS + 8 frags (q3)
// streamed from L2; amdgpu_waves_per_eu(2,2) pins the 256-reg/2-waves-per-EU
// tier so the allocator keeps weights resident (round-4 failure: needed ~280
// regs -> allocator demoted everything to per-step streaming, VGPR_Count=128).

typedef __attribute__((ext_vector_type(8))) short short8;
typedef __attribute__((ext_vector_type(4))) float float4v;

#define OFF_Y  ((size_t)0)
#define OFF_H2 ((size_t)2048*64)
#define OFF_R  ((size_t)2048*192)

// ---- d_ws byte offsets (all 64-aligned) ----
#define WS_FLAGS   0
#define WS_W1I     64           // [512][64]  bf16
#define WS_W1H     65600        // [512][128] bf16
#define WS_W2I     196672      // [512][128] bf16
#define WS_W2H     327744      // [512][128] bf16
#define WS_WK0     458816      // [128][192] bf16
#define WS_WK1     507968      // [128][128] bf16
#define WS_WK2     540736
#define WS_WK3     573504
#define WS_WK4     606272
#define WS_WK5     639040      // [64][128] bf16
#define WS_B1      655424      // [512] f32 (bih1+bhh1)
#define WS_B2      657472      // [512] f32
#define WS_BK0     659520      // [128] f32
#define WS_BK1     660032
#define WS_BK2     660544
#define WS_BK3     661056
#define WS_BK4     661568
#define WS_BK5     662080      // [64] f32
#define WS_RB      662336      // [2048][192] bf16

__device__ __forceinline__ float bf2f(unsigned short u){
  union { unsigned int i; float f; } c; c.i = ((unsigned int)u) << 16; return c.f;
}
__device__ __forceinline__ unsigned short f2bf(float f){
  union { float f; unsigned int i; } c; c.f = f;
  unsigned int x = c.i;
  unsigned int r = (x + 0x7FFFu + ((x >> 16) & 1u)) >> 16;   // RNE
  return (unsigned short)r;
}
__device__ __forceinline__ float sig_(float x){ return 1.0f/(1.0f + __expf(-x)); }
__device__ __forceinline__ float tanh_(float x){ return 2.0f/(1.0f + __expf(-2.0f*x)) - 1.0f; }

#define MFMA16(a,b,c) __builtin_amdgcn_mfma_f32_16x16x32_bf16((a),(b),(c),0,0,0)

__device__ __forceinline__ unsigned int ldx2(const void* x, size_t off, int f32){
  if (f32){
    const float* p = (const float*)x + off;
    return (unsigned int)f2bf(p[0]) | ((unsigned int)f2bf(p[1]) << 16);
  }
  return *(const unsigned int*)((const unsigned short*)x + off);
}
__device__ __forceinline__ float ld1f(const void* p, int i, int f32){
  if (f32) return ((const float*)p)[i];
  return bf2f(((const unsigned short*)p)[i]);
}
__device__ __forceinline__ void st1(void* o, size_t off, float v, int f32){
  if (f32) ((float*)o)[off] = v;
  else     ((unsigned short*)o)[off] = f2bf(v);
}

// ---------------------------------------------------------------------------
// dtype probe: flags[a]=1 iff array a is fp32 (verified round 3)
// ---------------------------------------------------------------------------
__global__ void probe_kernel(const void* x,
                             const void* w1i, const void* w1h,
                             const void* w2i, const void* w2h,
                             const void* k0, const void* k1, const void* k2,
                             const void* k3, const void* k4, const void* k5,
                             int* flags)
{
  const void* arrs[11] = {x, w1i, w1h, w2i, w2h, k0, k1, k2, k3, k4, k5};
  const int lane = threadIdx.x & 63;
  for (int a = 0; a < 11; a++){
    const unsigned short* p = (const unsigned short*)arrs[a];
    int bad = 0;
    #pragma unroll
    for (int j = 0; j < 8; j++){
      float v = bf2f(p[lane*8 + j]);
      if (!(v > -1e3f && v < 1e3f)) bad = 1;
    }
    unsigned long long m = __ballot(bad);
    if (lane == 0) flags[a] = (m != 0ull) ? 1 : 0;
  }
}

// ---------------------------------------------------------------------------
// convert: weights -> bf16 in ws; bias sums -> f32 in ws
// ---------------------------------------------------------------------------
__device__ __forceinline__ void conv_range(const void* src, unsigned short* dst,
                                           int lo, int n, int f32, int t){
  int hi = lo + 4096; if (hi > n) hi = n;
  for (int i = lo + t; i < hi; i += 256)
    dst[i] = f32 ? f2bf(((const float*)src)[i]) : ((const unsigned short*)src)[i];
}

__global__ void convert_kernel(const void* w1i, const void* w1h,
                               const void* w2i, const void* w2h,
                               const void* k0, const void* k1, const void* k2,
                               const void* k3, const void* k4, const void* k5,
                               const void* bi1, const void* bh1,
                               const void* bi2, const void* bh2,
                               const void* bb0, const void* bb1, const void* bb2,
                               const void* bb3, const void* bb4, const void* bb5,
                               char* ws)
{
  const int* flags = (const int*)(ws + WS_FLAGS);
  const int b = blockIdx.x, t = threadIdx.x;
  if      (b <  8) conv_range(w1i, (unsigned short*)(ws+WS_W1I), (b-0)*4096, 32768, flags[1], t);
  else if (b < 24) conv_range(w1h, (unsigned short*)(ws+WS_W1H), (b-8)*4096, 65536, flags[2], t);
  else if (b < 40) conv_range(w2i, (unsigned short*)(ws+WS_W2I), (b-24)*4096, 65536, flags[3], t);
  else if (b < 56) conv_range(w2h, (unsigned short*)(ws+WS_W2H), (b-40)*4096, 65536, flags[4], t);
  else if (b < 62) conv_range(k0,  (unsigned short*)(ws+WS_WK0), (b-56)*4096, 24576, flags[5], t);
  else if (b < 66) conv_range(k1,  (unsigned short*)(ws+WS_WK1), (b-62)*4096, 16384, flags[6], t);
  else if (b < 70) conv_range(k2,  (unsigned short*)(ws+WS_WK2), (b-66)*4096, 16384, flags[7], t);
  else if (b < 74) conv_range(k3,  (unsigned short*)(ws+WS_WK3), (b-70)*4096, 16384, flags[8], t);
  else if (b < 78) conv_range(k4,  (unsigned short*)(ws+WS_WK4), (b-74)*4096, 16384, flags[9], t);
  else if (b < 80) conv_range(k5,  (unsigned short*)(ws+WS_WK5), (b-78)*4096,  8192, flags[10], t);
  else {
    float* b1 = (float*)(ws+WS_B1);
    float* b2 = (float*)(ws+WS_B2);
    for (int i = t; i < 512; i += 256){
      b1[i] = ld1f(bi1, i, flags[1]) + ld1f(bh1, i, flags[2]);
      b2[i] = ld1f(bi2, i, flags[3]) + ld1f(bh2, i, flags[4]);
    }
    const void* bks[6] = {bb0, bb1, bb2, bb3, bb4, bb5};
    const size_t dof[6] = {WS_BK0, WS_BK1, WS_BK2, WS_BK3, WS_BK4, WS_BK5};
    for (int a = 0; a < 6; a++){
      int n = (a == 5) ? 64 : 128;
      float* d = (float*)(ws + dof[a]);
      for (int i = t; i < n; i += 256) d[i] = ld1f(bks[a], i, flags[5+a]);
    }
  }
}

// ---------------------------------------------------------------------------
// LSTM persistent kernel
// ---------------------------------------------------------------------------
__global__ __launch_bounds__(512)
__attribute__((amdgpu_waves_per_eu(2, 2)))
void lstm_kernel(const void* __restrict__ x,
                 const unsigned short* __restrict__ W1I,
                 const unsigned short* __restrict__ W1H,
                 const unsigned short* __restrict__ W2I,
                 const unsigned short* __restrict__ W2H,
                 const float* __restrict__ B1, const float* __restrict__ B2,
                 unsigned short* __restrict__ RB,
                 const int* __restrict__ flags,
                 void* __restrict__ out)
{
  __shared__ __align__(16) unsigned short A1s[2][16][200];  // [x(64)|h1(128)]
  __shared__ __align__(16) unsigned short A2s[2][16][264];  // [h1(128)|h2(128)]
  __shared__ __align__(16) short8 WPARK[8][4][64];          // w1 kc=0 (W1I lo), per wave/gate

  const int fx = flags[0];
  const int fo = fx;   // output dtype follows x

  const int tid  = threadIdx.x;
  const int w    = tid >> 6;
  const int lane = tid & 63;
  const int l15  = lane & 15;
  const int lq   = lane >> 4;
  const int r0   = blockIdx.x * 16;
  const int mycol = w*16 + l15;
  const int xm = tid >> 5;
  const int xc = (tid & 31) * 2;

  // ---- LDS-parked: w1 kc=0 (W1I cols 0..31), all 4 gates
  #pragma unroll
  for (int q = 0; q < 4; q++)
    WPARK[w][q][lane] = *(const short8*)(W1I + (size_t)(q*128 + mycol)*64 + lq*8);

  // ---- VGPR-resident: w1 kc=1..5 (20 frags), w2 q0..2 kc=0..7 (24 frags)
  short8 w1r[4][5];
  #pragma unroll
  for (int q = 0; q < 4; q++){
    const int n = q*128 + mycol;
    w1r[q][0] = *(const short8*)(W1I + (size_t)n*64 + 32 + lq*8);
    #pragma unroll
    for (int kc = 1; kc < 5; kc++)
      w1r[q][kc] = *(const short8*)(W1H + (size_t)n*128 + (kc-1)*32 + lq*8);
  }
  short8 w2r[3][8];
  #pragma unroll
  for (int q = 0; q < 3; q++){
    const int n = q*128 + mycol;
    #pragma unroll
    for (int kc = 0; kc < 8; kc++){
      const unsigned short* p = (kc < 4) ? (W2I + (size_t)n*128 + kc*32     + lq*8)
                                         : (W2H + (size_t)n*128 + (kc-4)*32 + lq*8);
      w2r[q][kc] = *(const short8*)p;
    }
  }
  // streamed q3 bases
  const unsigned short* sq3i = W2I + (size_t)(3*128 + mycol)*128 + lq*8;
  const unsigned short* sq3h = W2H + (size_t)(3*128 + mycol)*128 + lq*8;

  float b1[4], b2[4];
  #pragma unroll
  for (int q = 0; q < 4; q++){
    b1[q] = B1[q*128 + mycol];
    b2[q] = B2[q*128 + mycol];
  }

  for (int i = tid; i < 16*128; i += 512){
    int m = i >> 7, c = i & 127;
    A1s[0][m][64 + c]  = 0;
    A2s[0][m][128 + c] = 0;
  }
  *(unsigned int*)&A1s[0][xm][xc] =
      ldx2(x, (((size_t)(r0 + xm))*256 + 0)*64 + xc, fx);

  float c1r[4] = {0.f,0.f,0.f,0.f};
  float c2r[4] = {0.f,0.f,0.f,0.f};
  float h2f[4] = {0.f,0.f,0.f,0.f};
  unsigned short h2b[4] = {0,0,0,0};
  __syncthreads();

  for (int t = 0; t < 256; t++){
    const int buf = t & 1, nbuf = buf ^ 1;

    // prefetch x(t+1) (register load -> no barrier drain; ~full-step window)
    unsigned int xv = 0u;
    if (t < 255)
      xv = ldx2(x, (((size_t)(r0 + xm))*256 + (t+1))*64 + xc, fx);
    // streamed q3 first half (W2I), consumed in cell2
    short8 stq3[8];
    stq3[0] = *(const short8*)(sq3i + 0);
    stq3[1] = *(const short8*)(sq3i + 32);
    stq3[2] = *(const short8*)(sq3i + 64);
    stq3[3] = *(const short8*)(sq3i + 96);

    // ---- cell1: gates = [x_t | h1(t-1)] @ W1^T
    float4v acc[4];
    #pragma unroll
    for (int q = 0; q < 4; q++) acc[q] = (float4v){b1[q], b1[q], b1[q], b1[q]};
    {
      short8 af = *(const short8*)&A1s[buf][l15][lq*8];
      #pragma unroll
      for (int q = 0; q < 4; q++)
        acc[q] = MFMA16(af, WPARK[w][q][lane], acc[q]);
    }
    #pragma unroll
    for (int kc = 1; kc < 6; kc++){
      short8 af = *(const short8*)&A1s[buf][l15][kc*32 + lq*8];
      #pragma unroll
      for (int q = 0; q < 4; q++)
        acc[q] = MFMA16(af, w1r[q][kc-1], acc[q]);
    }

    // streamed q3 second half (W2H)
    stq3[4] = *(const short8*)(sq3h + 0);
    stq3[5] = *(const short8*)(sq3h + 32);
    stq3[6] = *(const short8*)(sq3h + 64);
    stq3[7] = *(const short8*)(sq3h + 96);

    unsigned short h1b[4];
    #pragma unroll
    for (int r = 0; r < 4; r++){
      float ig = sig_(acc[0][r]);
      float fg = sig_(acc[1][r]);
      float gg = tanh_(acc[2][r]);
      float og = sig_(acc[3][r]);
      c1r[r] = fg*c1r[r] + ig*gg;
      h1b[r] = f2bf(og * tanh_(c1r[r]));
    }
    #pragma unroll
    for (int r = 0; r < 4; r++){
      int row = lq*4 + r;
      A2s[buf][row][mycol]       = h1b[r];
      A1s[nbuf][row][64 + mycol] = h1b[r];
    }

    __syncthreads();   // h1(t) visible for cell2

    // ---- cell2: gates = [h1(t) | h2(t-1)] @ W2^T  (q0-2 resident, q3 streamed)
    #pragma unroll
    for (int q = 0; q < 4; q++) acc[q] = (float4v){b2[q], b2[q], b2[q], b2[q]};
    #pragma unroll
    for (int kc = 0; kc < 8; kc++){
      short8 af = *(const short8*)&A2s[buf][l15][kc*32 + lq*8];
      acc[0] = MFMA16(af, w2r[0][kc], acc[0]);
      acc[1] = MFMA16(af, w2r[1][kc], acc[1]);
      acc[2] = MFMA16(af, w2r[2][kc], acc[2]);
      acc[3] = MFMA16(af, stq3[kc],   acc[3]);
    }

    #pragma unroll
    for (int r = 0; r < 4; r++){
      float ig = sig_(acc[0][r]);
      float fg = sig_(acc[1][r]);
      float gg = tanh_(acc[2][r]);
      float og = sig_(acc[3][r]);
      c2r[r] = fg*c2r[r] + ig*gg;
      h2f[r] = og * tanh_(c2r[r]);
      h2b[r] = f2bf(h2f[r]);
    }
    #pragma unroll
    for (int r = 0; r < 4; r++){
      int row = lq*4 + r;
      A2s[nbuf][row][128 + mycol] = h2b[r];
    }
    if (t < 255)
      *(unsigned int*)&A1s[nbuf][xm][xc] = xv;
    __syncthreads();
  }

  // ---- epilogue: h2(T-1) outputs + r tail (x[:,255,:])
  #pragma unroll
  for (int r = 0; r < 4; r++){
    size_t grow = (size_t)(r0 + lq*4 + r);
    st1(out, OFF_H2 + grow*128 + mycol, h2f[r], fo);
    st1(out, OFF_R  + grow*192 + mycol, h2f[r], fo);
    RB[grow*192 + mycol] = h2b[r];
  }
  {
    size_t off = (((size_t)(r0 + xm))*256 + 255)*64 + xc;
    float v0, v1;
    if (fx){ const float* p = (const float*)x + off; v0 = p[0]; v1 = p[1]; }
    else   { const unsigned short* p = (const unsigned short*)x + off;
             v0 = bf2f(p[0]); v1 = bf2f(p[1]); }
    size_t rrow = (size_t)(r0 + xm)*192 + 128 + xc;
    st1(out, OFF_R + rrow,     v0, fo);
    st1(out, OFF_R + rrow + 1, v1, fo);
    RB[rrow]     = f2bf(v0);
    RB[rrow + 1] = f2bf(v1);
  }
}

// ---------------------------------------------------------------------------
// KDN with MFMA: r[2048,192] -> 128 x5 (ReLU) -> 64
// ---------------------------------------------------------------------------
__global__ __launch_bounds__(256)
void kdn_kernel(const char* __restrict__ ws, void* __restrict__ out)
{
  __shared__ __align__(16) unsigned short bufA[16][200];
  __shared__ __align__(16) unsigned short bufB[16][200];

  const int* flags = (const int*)(ws + WS_FLAGS);
  const int fo = flags[0];

  const int tid = threadIdx.x;
  const int w    = tid >> 6;
  const int lane = tid & 63;
  const int l15  = lane & 15;
  const int lq   = lane >> 4;
  const int r0  = blockIdx.x * 16;

  const unsigned short* RB = (const unsigned short*)(ws + WS_RB);

  for (int i = tid; i < 1536; i += 256){
    int row = i / 96, c2 = (i % 96) * 2;
    *(unsigned int*)&bufA[row][c2] =
        *(const unsigned int*)&RB[(size_t)(r0 + row)*192 + c2];
  }
  __syncthreads();

  const unsigned short* WK[6] = {
    (const unsigned short*)(ws+WS_WK0), (const unsigned short*)(ws+WS_WK1),
    (const unsigned short*)(ws+WS_WK2), (const unsigned short*)(ws+WS_WK3),
    (const unsigned short*)(ws+WS_WK4), (const unsigned short*)(ws+WS_WK5)};
  const float* BK[6] = {
    (const float*)(ws+WS_BK0), (const float*)(ws+WS_BK1),
    (const float*)(ws+WS_BK2), (const float*)(ws+WS_BK3),
    (const float*)(ws+WS_BK4), (const float*)(ws+WS_BK5)};

  unsigned short (*src)[200] = bufA;
  unsigned short (*dst)[200] = bufB;

  #pragma unroll
  for (int l = 0; l < 5; l++){
    const int K = (l == 0) ? 192 : 128;
    const int nk = K / 32;
    #pragma unroll
    for (int tau = 0; tau < 2; tau++){
      const int n = w*32 + tau*16 + l15;
      float bv = BK[l][n];
      float4v acc = {bv, bv, bv, bv};
      for (int kc = 0; kc < nk; kc++){
        short8 af = *(const short8*)&src[l15][kc*32 + lq*8];
        short8 wf = *(const short8*)(WK[l] + (size_t)n*K + kc*32 + lq*8);
        acc = MFMA16(af, wf, acc);
      }
      #pragma unroll
      for (int r = 0; r < 4; r++)
        dst[lq*4 + r][n] = f2bf(fmaxf(acc[r], 0.0f));
    }
    __syncthreads();
    unsigned short (*tmp)[200] = src; src = dst; dst = tmp;
  }

  {
    const int n = w*16 + l15;
    float bv = BK[5][n];
    float4v acc = {bv, bv, bv, bv};
    #pragma unroll
    for (int kc = 0; kc < 4; kc++){
      short8 af = *(const short8*)&src[l15][kc*32 + lq*8];
      short8 wf = *(const short8*)(WK[5] + (size_t)n*128 + kc*32 + lq*8);
      acc = MFMA16(af, wf, acc);
    }
    #pragma unroll
    for (int r = 0; r < 4; r++)
      st1(out, OFF_Y + (size_t)(r0 + lq*4 + r)*64 + n, acc[r], fo);
  }
}

// ---------------------------------------------------------------------------
extern "C" void kernel_launch(void* const* d_in, const int* in_sizes, int n_in,
                              void* d_out, int out_size, void* d_ws, size_t ws_size,
                              hipStream_t stream)
{
  (void)in_sizes; (void)n_in; (void)ws_size; (void)out_size;

  const void* x    = d_in[0];
  const void* Wih1 = d_in[1];
  const void* Whh1 = d_in[2];
  const void* bih1 = d_in[3];
  const void* bhh1 = d_in[4];
  const void* Wih2 = d_in[5];
  const void* Whh2 = d_in[6];
  const void* bih2 = d_in[7];
  const void* bhh2 = d_in[8];
  const void* Wk0 = d_in[9];  const void* bk0 = d_in[10];
  const void* Wk1 = d_in[11]; const void* bk1 = d_in[12];
  const void* Wk2 = d_in[13]; const void* bk2 = d_in[14];
  const void* Wk3 = d_in[15]; const void* bk3 = d_in[16];
  const void* Wk4 = d_in[17]; const void* bk4 = d_in[18];
  const void* Wk5 = d_in[19]; const void* bk5 = d_in[20];

  char* ws = (char*)d_ws;

  hipLaunchKernelGGL(probe_kernel, dim3(1), dim3(64), 0, stream,
                     x, Wih1, Whh1, Wih2, Whh2,
                     Wk0, Wk1, Wk2, Wk3, Wk4, Wk5, (int*)(ws + WS_FLAGS));
  hipLaunchKernelGGL(convert_kernel, dim3(81), dim3(256), 0, stream,
                     Wih1, Whh1, Wih2, Whh2,
                     Wk0, Wk1, Wk2, Wk3, Wk4, Wk5,
                     bih1, bhh1, bih2, bhh2,
                     bk0, bk1, bk2, bk3, bk4, bk5, ws);
  hipLaunchKernelGGL(lstm_kernel, dim3(128), dim3(512), 0, stream,
                     x,
                     (const unsigned short*)(ws + WS_W1I),
                     (const unsigned short*)(ws + WS_W1H),
                     (const unsigned short*)(ws + WS_W2I),
                     (const unsigned short*)(ws + WS_W2H),
                     (const float*)(ws + WS_B1), (const float*)(ws + WS_B2),
                     (unsigned short*)(ws + WS_RB),
                     (const int*)(ws + WS_FLAGS),
                     d_out);
  hipLaunchKernelGGL(kdn_kernel, dim3(128), dim3(256), 0, stream,
                     ws, d_out);
}